// Round 7
// baseline (102.229 us; speedup 1.0000x reference)
//
#include <hip/hip_runtime.h>
#include <cstdint>

#define EMBED      2048
#define NEXP       16
#define NWAVES     4                   // d-split waves per block (512 d each)
#define TOKB       64                  // tokens per block
#define NTOK_TOTAL (8 * 4096)
#define WOFF       (NTOK_TOTAL * 2)    // float offset of indices region in d_out
#define DPW        512                 // d per wave
#define DPL        128                 // d per lane (one s-subgroup slice)

__device__ __forceinline__ void g2l16(const float* g, float* l) {
    __builtin_amdgcn_global_load_lds(
        (const __attribute__((address_space(1))) void*)(uintptr_t)g,
        (__attribute__((address_space(3))) void*)(uintptr_t)l, 16, 0, 0);
}

// quad_perm DPP xor-swap within groups of 4 lanes (VALU, no LDS latency)
__device__ __forceinline__ float qswap(float v, const int which) {
    const int iv = __builtin_bit_cast(int, v);
    int r;
    if (which == 1) r = __builtin_amdgcn_mov_dpp(iv, 0xB1, 0xf, 0xf, false); // [1,0,3,2]
    else            r = __builtin_amdgcn_mov_dpp(iv, 0x4E, 0xf, 0xf, false); // [2,3,0,1]
    return __builtin_bit_cast(float, r);
}

// Barrier-free persistent-W router:
//  - lane = (e = lane>>2, s = lane&3). Wave w owns d in [w*512, w*512+512).
//  - W[e][lane's 128-d slice] lives in 128 VGPRs, loaded once (L2-hot, 64 MB
//    total across grid). ZERO W operands through LDS/SMEM/VMEM in the loop.
//  - x staged into a per-wave 4-slot LDS ring by global_load_lds with an
//    XOR-swizzled SOURCE (slot q holds granule q^((q>>5)&3)) so the 4
//    s-groups read 4 distinct bank-quads -> conflict-free broadcast reads.
//  - NO barriers in the main loop: each wave reads only its own staging,
//    ordered by counted s_waitcnt vmcnt(2) (reader slot t&3, writer slot
//    (t+2)&3 -> 2 slots apart, no ring race).
//  - acc is ONE scalar per lane; fold over s = 2 quad_perm DPP + 2 adds.
extern "C" __global__ __launch_bounds__(NWAVES * 64, 2)
void router_kernel(const float* __restrict__ x,
                   const float* __restrict__ gw,
                   float* __restrict__ out)
{
    __shared__ float xs[NWAVES][4][DPW];        // 32 KB staging rings
    __shared__ float part[TOKB][NWAVES][NEXP];  // 16 KB partial logits

    const int tid  = threadIdx.x;
    const int lane = tid & 63;
    const int w    = __builtin_amdgcn_readfirstlane(tid >> 6);
    const int s    = lane & 3;          // d-subgroup
    const int e    = lane >> 2;         // expert
    const int t0   = blockIdx.x * TOKB;

    // ---- W preload: 32 float4 = this lane's 128-d slice of expert e ----
    float4 Wr[32];
    {
        const float4* wsrc = (const float4*)(gw + (size_t)e * EMBED + w * DPW + s * DPL);
#pragma unroll
        for (int j = 0; j < 32; ++j) Wr[j] = wsrc[j];
    }

    // stage token t's 512-float slice into slot: linear LDS dest (lane x 16B),
    // global source granule h = L ^ ((L>>5)&3)  (bank-spread involution)
    auto stage = [&](int t, int slot) {
        const float* src = x + (size_t)(t0 + t) * EMBED + w * DPW;
#pragma unroll
        for (int i2 = 0; i2 < 2; ++i2) {
            const int L = lane + i2 * 64;          // granule slot 0..127
            const int h = L ^ ((L >> 5) & 3);      // source granule
            g2l16(src + h * 4, &xs[w][slot][L * 4]);
        }
    };

    // prologue: stage tokens 0,1 (W loads are older in the vmcnt queue, so
    // the first counted wait below also guarantees Wr is resident)
    stage(0, 0);
    stage(1, 1);

    for (int t = 0; t < TOKB; ++t) {
        if (t < TOKB - 2) asm volatile("s_waitcnt vmcnt(2)" ::: "memory");
        else              asm volatile("s_waitcnt vmcnt(0)" ::: "memory");

        const float* bx = &xs[w][t & 3][0];
        float acc = 0.0f;
#pragma unroll
        for (int j = 0; j < 32; ++j) {
            const int q = (s * 32 + j) ^ s;        // swizzled granule slot
            const float4 x4 = *(const float4*)(bx + q * 4);
            acc = fmaf(x4.x, Wr[j].x, acc);
            acc = fmaf(x4.y, Wr[j].y, acc);
            acc = fmaf(x4.z, Wr[j].z, acc);
            acc = fmaf(x4.w, Wr[j].w, acc);
        }
        // fold the 4 s-subgroups (quad_perm DPP: xor1 then xor2)
        acc += qswap(acc, 1);
        acc += qswap(acc, 2);
        if (s == 0) part[t][w][e] = acc;

        if (t + 2 < TOKB) stage(t + 2, (t + 2) & 3);
    }
    __syncthreads();

    // ---- finalize: group g = tid>>4 handles tokens {g, g+16, g+32, g+48} ----
    {
        const int g  = tid >> 4;
        const int le = tid & 15;
#pragma unroll
        for (int r = 0; r < 4; ++r) {
            const int t = g + r * 16;
            float lg = part[t][0][le] + part[t][1][le]
                     + part[t][2][le] + part[t][3][le];

            // shfl-tournament top-2 over the 16 lanes of this group,
            // lowest-index tie-break (matches lax.top_k ordering)
            float m1 = lg;        int i1 = le;
            float m2 = -INFINITY; int i2 = NEXP;
#pragma unroll
            for (int d = 1; d < 16; d <<= 1) {
                const float b1 = __shfl_xor(m1, d, 64);
                const int  ib1 = __shfl_xor(i1, d, 64);
                const float b2 = __shfl_xor(m2, d, 64);
                const int  ib2 = __shfl_xor(i2, d, 64);
                const bool bwin = (b1 > m1) || (b1 == m1 && ib1 < i1);
                const float w1v = bwin ? b1 : m1; const int w1i = bwin ? ib1 : i1;
                const float l1v = bwin ? m1 : b1; const int l1i = bwin ? i1 : ib1;
                const float c2v = bwin ? b2 : m2; const int c2i = bwin ? ib2 : i2;
                const bool sw = (c2v > l1v) || (c2v == l1v && c2i < l1i);
                m1 = w1v; i1 = w1i;
                m2 = sw ? c2v : l1v; i2 = sw ? c2i : l1i;
            }
            if (le == 0) {
                const float ed = __expf(m2 - m1);   // <= 1
                const float p1 = 1.0f / (1.0f + ed);
                const int tok = t0 + t;
                out[tok * 2 + 0] = p1;
                out[tok * 2 + 1] = 1.0f - p1;
                out[WOFF + tok * 2 + 0] = (float)i1;
                out[WOFF + tok * 2 + 1] = (float)i2;
            }
        }
    }
}

extern "C" void kernel_launch(void* const* d_in, const int* in_sizes, int n_in,
                              void* d_out, int out_size, void* d_ws, size_t ws_size,
                              hipStream_t stream) {
    const float* x  = (const float*)d_in[0];   // [8,4096,2048] f32
    const float* gw = (const float*)d_in[1];   // [16,2048] f32
    float* out = (float*)d_out;                // weights[65536] ++ indices-as-f32[65536]

    const int nblocks = NTOK_TOTAL / TOKB;     // 512 blocks x 256 threads
    router_kernel<<<dim3(nblocks), dim3(NWAVES * 64), 0, stream>>>(x, gw, out);
}

// Round 8
// 71.100 us; speedup vs baseline: 1.4378x; 1.4378x over previous
//
#include <hip/hip_runtime.h>
#include <cstdint>

#define EMBED      2048
#define NEXP       16
#define NWAVES     8                    // d-split waves per block
#define TOKB       128                  // tokens per block (TWO per lane)
#define WINF       64                   // floats per window per token
#define NWIN       (EMBED / WINF)       // 32 windows
#define NBUF       4                    // pipeline depth
#define NTOK_TOTAL (8 * 4096)
#define WOFF       (NTOK_TOTAL * 2)     // float offset of indices region in d_out
#define PAD        17                   // epilogue LDS row pad

__device__ __forceinline__ void g2l16(const float* g, float* l) {
    __builtin_amdgcn_global_load_lds(
        (const __attribute__((address_space(1))) void*)(uintptr_t)g,
        (__attribute__((address_space(3))) void*)(uintptr_t)l, 16, 0, 0);
}
__device__ __forceinline__ void g2l4(const float* g, float* l) {
    __builtin_amdgcn_global_load_lds(
        (const __attribute__((address_space(1))) void*)(uintptr_t)g,
        (__attribute__((address_space(3))) void*)(uintptr_t)l, 4, 0, 0);
}

// R8: attacks BOTH residual walls at once.
//  (1) LDS instr count: 2 tokens/lane -> each broadcast W float4 feeds 8 FMAs
//      instead of 4 -> W ds_read_b128 per CU halves (16384 -> 8192).
//  (2) Memory burstiness: R4/R6's per-window vmcnt(0)+barrier drain exposed a
//      ~2500cy latency tail every window (8976cy measured vs ~6400cy service).
//      4-deep ring + counted vmcnt(12): the window being consumed was issued
//      3 windows (~10K cy) earlier -> pure service-limited streaming.
//  Geometry: 256 blocks x 512 thr (1 block/CU), LDS 144 KB, 8 waves/CU.
//  Per window/thread: 4 g2l16 (x) + 2 g2l4 (W) = 6 loads, uniform per wave.
extern "C" __global__ __launch_bounds__(NWAVES * 64, 2)
void router_kernel(const float* __restrict__ x,
                   const float* __restrict__ gw,
                   float* __restrict__ out)
{
    __shared__ float lds_x[NBUF][TOKB * WINF];   // 4 x 32 KB
    __shared__ float lds_w[NBUF][NEXP * WINF];   // 4 x  4 KB

    const int tid  = threadIdx.x;
    const int lane = tid & 63;
    const int W    = __builtin_amdgcn_readfirstlane(tid >> 6);
    const int t0   = blockIdx.x * TOKB;

    float acc0[NEXP], acc1[NEXP];
#pragma unroll
    for (int e = 0; e < NEXP; ++e) { acc0[e] = 0.0f; acc1[e] = 0.0f; }

    // stage window win into ring slot buf.
    // x: 2048 granules (16B), 4/thread. LDS linear at L; source granule
    // inverse-swizzled: gsrc = slot ^ (row&15)  (XOR involution; reader uses
    // the same formula, spreading the 64-lane column read across all slots)
    // W: 1024 dwords, 2/thread, linear (read wave-uniform -> broadcast).
    auto stage = [&](int win, int buf) {
#pragma unroll
        for (int it = 0; it < 4; ++it) {
            const int L    = it * 512 + tid;
            const int row  = L >> 4;           // 0..127 local token
            const int slot = L & 15;           // granule slot in row
            const int gsrc = slot ^ (row & 15);
            g2l16(x + (size_t)(t0 + row) * EMBED + win * WINF + gsrc * 4,
                  &lds_x[buf][L * 4]);
        }
#pragma unroll
        for (int it = 0; it < 2; ++it) {
            const int q = it * 512 + tid;
            const int e = q >> 6, f = q & 63;
            g2l4(gw + e * EMBED + win * WINF + f, &lds_w[buf][q]);
        }
    };

    // one window: per lane 4 swizzled x b128 (2 granules x 2 token-rows) +
    // 32 broadcast W b128, 256 FMAs
    auto compute = [&](int buf) {
        const float* bx = lds_x[buf];
        const float* bw = lds_w[buf];
#pragma unroll
        for (int j = 0; j < 2; ++j) {
            const int g    = W * 2 + j;                // my granule 0..15
            const int slot = (g ^ lane) & 15;          // swizzled slot
            const float4 xa = *(const float4*)&bx[lane * WINF + slot * 4];
            const float4 xb = *(const float4*)&bx[(lane + 64) * WINF + slot * 4];
#pragma unroll
            for (int e = 0; e < NEXP; ++e) {
                const float4 w4 = *(const float4*)&bw[e * WINF + g * 4];
                acc0[e] = fmaf(xa.x, w4.x, acc0[e]);
                acc0[e] = fmaf(xa.y, w4.y, acc0[e]);
                acc0[e] = fmaf(xa.z, w4.z, acc0[e]);
                acc0[e] = fmaf(xa.w, w4.w, acc0[e]);
                acc1[e] = fmaf(xb.x, w4.x, acc1[e]);
                acc1[e] = fmaf(xb.y, w4.y, acc1[e]);
                acc1[e] = fmaf(xb.z, w4.z, acc1[e]);
                acc1[e] = fmaf(xb.w, w4.w, acc1[e]);
            }
        }
    };

    // prologue: 3 windows in flight (18 loads/thread)
    stage(0, 0); stage(1, 1); stage(2, 2);

    // main: window k ready when only k+1,k+2 outstanding (12 loads)
    for (int k = 0; k <= NWIN - 3; ++k) {
        asm volatile("s_waitcnt vmcnt(12) lgkmcnt(0)" ::: "memory");
        __builtin_amdgcn_s_barrier();
        asm volatile("" ::: "memory");
        if (k + 3 < NWIN) stage(k + 3, (k + 3) & 3);
        compute(k & 3);
    }
    asm volatile("s_waitcnt vmcnt(6) lgkmcnt(0)" ::: "memory");
    __builtin_amdgcn_s_barrier();
    asm volatile("" ::: "memory");
    compute((NWIN - 2) & 3);
    asm volatile("s_waitcnt vmcnt(0) lgkmcnt(0)" ::: "memory");
    __builtin_amdgcn_s_barrier();
    asm volatile("" ::: "memory");
    compute((NWIN - 1) & 3);

    __syncthreads();   // all reads of lds_x done before overlay

    // cross-wave reduction: part[wave][token][e], stride-17 rows (conflict-free)
    float (*part)[TOKB][PAD] = (float (*)[TOKB][PAD])lds_x;
#pragma unroll
    for (int e = 0; e < NEXP; ++e) {
        part[W][lane][e]      = acc0[e];
        part[W][lane + 64][e] = acc1[e];
    }
    __syncthreads();

    if (tid < TOKB) {                 // 2 waves finalize 128 tokens
        float tot[NEXP];
#pragma unroll
        for (int e = 0; e < NEXP; ++e) tot[e] = 0.0f;
#pragma unroll
        for (int w = 0; w < NWAVES; ++w) {
#pragma unroll
            for (int e = 0; e < NEXP; ++e) tot[e] += part[w][tid][e];
        }

        // top-2 with lowest-index tie-break (strict >), matches lax.top_k
        float m1 = tot[0]; int i1 = 0;
#pragma unroll
        for (int e = 1; e < NEXP; ++e) {
            if (tot[e] > m1) { m1 = tot[e]; i1 = e; }
        }
        float m2 = -INFINITY; int i2 = 0;
#pragma unroll
        for (int e = 0; e < NEXP; ++e) {
            const bool sel = (e != i1) && (tot[e] > m2);
            if (sel) { m2 = tot[e]; i2 = e; }
        }

        // normalized top-2 weights = softmax over the two logits
        const float ed = __expf(m2 - m1);   // <= 1
        const float w1 = 1.0f / (1.0f + ed);
        const float w2 = 1.0f - w1;

        const int t = t0 + tid;
        out[t * 2 + 0] = w1;
        out[t * 2 + 1] = w2;
        out[WOFF + t * 2 + 0] = (float)i1;
        out[WOFF + t * 2 + 1] = (float)i2;
    }
}

extern "C" void kernel_launch(void* const* d_in, const int* in_sizes, int n_in,
                              void* d_out, int out_size, void* d_ws, size_t ws_size,
                              hipStream_t stream) {
    const float* x  = (const float*)d_in[0];   // [8,4096,2048] f32
    const float* gw = (const float*)d_in[1];   // [16,2048] f32
    float* out = (float*)d_out;                // weights[65536] ++ indices-as-f32[65536]

    const int nblocks = NTOK_TOTAL / TOKB;     // 256 blocks x 512 threads
    router_kernel<<<dim3(nblocks), dim3(NWAVES * 64), 0, stream>>>(x, gw, out);
}

// Round 9
// 58.816 us; speedup vs baseline: 1.7381x; 1.2088x over previous
//
#include <hip/hip_runtime.h>
#include <cstdint>

#define EMBED      2048
#define NEXP       16
#define NWAVES     8                   // d-split waves per block
#define TOKB       64                  // tokens per block
#define DPW        256                 // d per wave
#define NTOK_TOTAL (8 * 4096)
#define WOFF       (NTOK_TOTAL * 2)    // float offset of indices region in d_out
#define PAD        17                  // part row pad (conflict-free)

// DPP quad_perm xor swaps (pure VALU, no LDS pipe)
__device__ __forceinline__ float dpp_xor1(float v) {
    return __builtin_bit_cast(float,
        __builtin_amdgcn_mov_dpp(__builtin_bit_cast(int, v), 0xB1, 0xF, 0xF, false));
}
__device__ __forceinline__ float dpp_xor2(float v) {
    return __builtin_bit_cast(float,
        __builtin_amdgcn_mov_dpp(__builtin_bit_cast(int, v), 0x4E, 0xF, 0xF, false));
}
// ds_swizzle BitMode xor within 32-lane halves (imm = xor<<10 | 0x1F)
template <int IMM>
__device__ __forceinline__ float swz(float v) {
    return __builtin_bit_cast(float,
        __builtin_amdgcn_ds_swizzle(__builtin_bit_cast(int, v), IMM));
}

// W-in-VGPR router. wave = 256-d slice, lane = 4 consecutive d.
//  - W[e][lane's 4 d] preloaded once: 64 VGPRs. No W traffic in the loop,
//    no broadcast reads (the wall in R4/R5/R8: 16K broadcast b128/CU ~ 60us).
//  - x: ONE perfectly-coalesced float4 wave-load per (wave, token); no LDS
//    staging, no barriers in the main loop; 4-slot register prefetch ring.
//  - per token: 64 fmaf -> 16 expert-partials/lane -> butterfly fold
//    (cndmask + quad_perm DPP for xor1/2, ds_swizzle xor4/8/16, shfl xor32):
//    lane j<16 ends with expert bitrev4(j)'s full 256-d partial dot.
//  - one sparse ds_write per (wave, token); single barrier; finalize = R8's
//    proven epilogue with the bitrev4 permutation folded in at compile time.
extern "C" __global__ __launch_bounds__(NWAVES * 64, 4)
void router_kernel(const float* __restrict__ x,
                   const float* __restrict__ gw,
                   float* __restrict__ out)
{
    __shared__ float part[NWAVES][TOKB][PAD];   // 34.8 KB -> 2 blocks/CU

    const int tid  = threadIdx.x;
    const int lane = tid & 63;
    const int w    = __builtin_amdgcn_readfirstlane(tid >> 6);
    const int t0   = blockIdx.x * TOKB;

    // ---- W preload: 16 experts x this lane's 4-d slice = 64 VGPRs ----
    float4 Wr[NEXP];
#pragma unroll
    for (int e = 0; e < NEXP; ++e)
        Wr[e] = *(const float4*)(gw + (size_t)e * EMBED + w * DPW + lane * 4);

    const float* xb = x + (size_t)t0 * EMBED + w * DPW + lane * 4;
    const bool b1 = lane & 1, b2 = lane & 2, b4 = lane & 4, b8 = lane & 8;

    auto proc = [&](int t, float4 x4) {
        float a[NEXP];
#pragma unroll
        for (int e = 0; e < NEXP; ++e) {
            a[e] = x4.x * Wr[e].x;
            a[e] = fmaf(x4.y, Wr[e].y, a[e]);
            a[e] = fmaf(x4.z, Wr[e].z, a[e]);
            a[e] = fmaf(x4.w, Wr[e].w, a[e]);
        }
        // fold 16 values over 64 lanes; keep/give butterfly
#pragma unroll
        for (int i = 0; i < 8; ++i) {              // xor1: 16 -> 8
            const float keep = b1 ? a[i + 8] : a[i];
            const float give = b1 ? a[i] : a[i + 8];
            a[i] = keep + dpp_xor1(give);
        }
#pragma unroll
        for (int i = 0; i < 4; ++i) {              // xor2: 8 -> 4
            const float keep = b2 ? a[i + 4] : a[i];
            const float give = b2 ? a[i] : a[i + 4];
            a[i] = keep + dpp_xor2(give);
        }
#pragma unroll
        for (int i = 0; i < 2; ++i) {              // xor4: 4 -> 2
            const float keep = b4 ? a[i + 2] : a[i];
            const float give = b4 ? a[i] : a[i + 2];
            a[i] = keep + swz<0x101F>(give);
        }
        {                                          // xor8: 2 -> 1
            const float keep = b8 ? a[1] : a[0];
            const float give = b8 ? a[0] : a[1];
            a[0] = keep + swz<0x201F>(give);
        }
        a[0] += swz<0x401F>(a[0]);                 // xor16
        a[0] += __shfl_xor(a[0], 32, 64);          // xor32
        if (lane < NEXP) part[w][t][lane] = a[0];  // 16 consecutive banks
    };

    // ---- main loop: 4-token register prefetch ring, no barriers ----
    float4 xp0 = *(const float4*)(xb + (size_t)0 * EMBED);
    float4 xp1 = *(const float4*)(xb + (size_t)1 * EMBED);
    float4 xp2 = *(const float4*)(xb + (size_t)2 * EMBED);
    float4 xp3 = *(const float4*)(xb + (size_t)3 * EMBED);
    for (int t = 0; t < TOKB - 4; t += 4) {
        proc(t + 0, xp0); xp0 = *(const float4*)(xb + (size_t)(t + 4) * EMBED);
        proc(t + 1, xp1); xp1 = *(const float4*)(xb + (size_t)(t + 5) * EMBED);
        proc(t + 2, xp2); xp2 = *(const float4*)(xb + (size_t)(t + 6) * EMBED);
        proc(t + 3, xp3); xp3 = *(const float4*)(xb + (size_t)(t + 7) * EMBED);
    }
    proc(TOKB - 4, xp0);
    proc(TOKB - 3, xp1);
    proc(TOKB - 2, xp2);
    proc(TOKB - 1, xp3);

    __syncthreads();

    // ---- finalize (R8 epilogue + bitrev4 slot->expert permutation) ----
    if (tid < TOKB) {
        constexpr int SIG[NEXP] = {0, 8, 4, 12, 2, 10, 6, 14,
                                   1, 9, 5, 13, 3, 11, 7, 15};
        float tot[NEXP];
#pragma unroll
        for (int e = 0; e < NEXP; ++e) tot[e] = 0.0f;
#pragma unroll
        for (int wv = 0; wv < NWAVES; ++wv) {
#pragma unroll
            for (int j = 0; j < NEXP; ++j) tot[SIG[j]] += part[wv][tid][j];
        }

        // top-2 with lowest-index tie-break (strict >), matches lax.top_k
        float m1 = tot[0]; int i1 = 0;
#pragma unroll
        for (int e = 1; e < NEXP; ++e) {
            if (tot[e] > m1) { m1 = tot[e]; i1 = e; }
        }
        float m2 = -INFINITY; int i2 = 0;
#pragma unroll
        for (int e = 0; e < NEXP; ++e) {
            const bool sel = (e != i1) && (tot[e] > m2);
            if (sel) { m2 = tot[e]; i2 = e; }
        }

        // normalized top-2 weights = softmax over the two logits
        const float ed = __expf(m2 - m1);   // <= 1
        const float w1 = 1.0f / (1.0f + ed);
        const float w2 = 1.0f - w1;

        const int t = t0 + tid;
        out[t * 2 + 0] = w1;
        out[t * 2 + 1] = w2;
        out[WOFF + t * 2 + 0] = (float)i1;
        out[WOFF + t * 2 + 1] = (float)i2;
    }
}

extern "C" void kernel_launch(void* const* d_in, const int* in_sizes, int n_in,
                              void* d_out, int out_size, void* d_ws, size_t ws_size,
                              hipStream_t stream) {
    const float* x  = (const float*)d_in[0];   // [8,4096,2048] f32
    const float* gw = (const float*)d_in[1];   // [16,2048] f32
    float* out = (float*)d_out;                // weights[65536] ++ indices-as-f32[65536]

    const int nblocks = NTOK_TOTAL / TOKB;     // 512 blocks x 512 threads
    router_kernel<<<dim3(nblocks), dim3(NWAVES * 64), 0, stream>>>(x, gw, out);
}